// Round 9
// baseline (342.777 us; speedup 1.0000x reference)
//
#include <hip/hip_runtime.h>
#include <math.h>

#define D   128
#define HH  4
#define HD  32
#define HID 512
#define WPB 4     // nodes (waves) per block in fused attention
#define MT  32    // node tile for k1
#define XP  136   // 128+8 padded LDS row (bf16 elems)
#define KVB 264   // 256+8 padded kv LDS row (bytes)
#define SCB 1024  // elems per scan block

typedef __attribute__((ext_vector_type(8))) short bf16x8;  // 8 bf16 (4 VGPRs)
typedef __attribute__((ext_vector_type(4))) float f32x4;   // MFMA C/D frag
typedef __attribute__((ext_vector_type(2))) float f32x2;

// fp32 -> bf16 bits, round-to-nearest-even
__device__ __forceinline__ short f2b(float f) {
    unsigned u = __float_as_uint(f);
    unsigned r = (u + 0x7FFFu + ((u >> 16) & 1u)) >> 16;
    return (short)r;
}
__device__ __forceinline__ float b2f(short s) {
    return __uint_as_float(((unsigned)(unsigned short)s) << 16);
}
// fp32 -> fp8 e4m3 (OCP on gfx950), via hw packed cvt
__device__ __forceinline__ unsigned char f2fp8(float f) {
    return (unsigned char)(__builtin_amdgcn_cvt_pk_fp8_f32(f, f, 0, false) & 0xFF);
}

// gelu tanh-approx via hw exp: 0.5x(1+tanh u) = x*e^{2u}/(e^{2u}+1)
__device__ __forceinline__ float gelu_tanh(float x) {
    float u = 0.7978845608028654f * (x + 0.044715f * x * x * x);
    float e = __expf(2.0f * u);
    return x * e * __builtin_amdgcn_rcpf(e + 1.0f);
}

// ---------- K0: zero degree array ----------
__global__ void k0_zero_deg(int* __restrict__ deg, int N) {
    int i = blockIdx.x * blockDim.x + threadIdx.x;
    if (i < N) deg[i] = 0;
}

// ---------- prep: all weights -> bf16 transposed [n][k] ----------
__global__ void k_prep(const float* __restrict__ W1, const float* __restrict__ W2,
                       const float* __restrict__ Wq, const float* __restrict__ Wk,
                       const float* __restrict__ Wv, const float* __restrict__ Wo,
                       short* __restrict__ Wt1, short* __restrict__ Wt2,
                       short* __restrict__ Wtq, short* __restrict__ Wtk,
                       short* __restrict__ Wtv, short* __restrict__ Wto) {
    int i = blockIdx.x * 256 + threadIdx.x;     // 65536 threads
    {   int n = i >> 7, k = i & 127; Wt1[i] = f2b(W1[k * HID + n]); }
    {   int n = i >> 9, k = i & 511; Wt2[i] = f2b(W2[k * D + n]); }
    if (i < D * D) {
        int n = i >> 7, k = i & 127;
        Wtq[i] = f2b(Wq[k * D + n]);
        Wtk[i] = f2b(Wk[k * D + n]);
        Wtv[i] = f2b(Wv[k * D + n]);
        Wto[i] = f2b(Wo[k * D + n]);
    }
}

// ---------- K1 (MFMA): q fp32, kv fp8 in 8-dim blocks ----------
__global__ __launch_bounds__(256) void k1_qkv_mfma(
        const float* __restrict__ x,
        const short* __restrict__ Wtq, const float* __restrict__ bq,
        const short* __restrict__ Wtk, const float* __restrict__ bk,
        const short* __restrict__ Wtv, const float* __restrict__ bv,
        float* __restrict__ q, unsigned char* __restrict__ kv, int N) {
    __shared__ short xs[MT * XP];
    __shared__ unsigned char kvs[MT * KVB];
    int m0 = blockIdx.x * MT;
    int t = threadIdx.x;
    int wave = t >> 6, lane = t & 63, quad = lane >> 4, l16 = lane & 15;

    {
        int row = t >> 3, c0 = (t & 7) * 16;
        int n = m0 + row;
        #pragma unroll
        for (int c = 0; c < 16; c += 4) {
            float4 xv = {0.f, 0.f, 0.f, 0.f};
            if (n < N) xv = *(const float4*)(x + (size_t)n * D + c0 + c);
            xs[row * XP + c0 + c + 0] = f2b(xv.x);
            xs[row * XP + c0 + c + 1] = f2b(xv.y);
            xs[row * XP + c0 + c + 2] = f2b(xv.z);
            xs[row * XP + c0 + c + 3] = f2b(xv.w);
        }
    }
    __syncthreads();

    f32x4 accq[2][2], acck[2][2], accv[2][2];
    #pragma unroll
    for (int nt = 0; nt < 2; ++nt) {
        int c = wave * 32 + nt * 16 + l16;
        float q0 = bq[c], k0 = bk[c], v0 = bv[c];
        #pragma unroll
        for (int mt = 0; mt < 2; ++mt) {
            accq[mt][nt] = (f32x4){q0, q0, q0, q0};
            acck[mt][nt] = (f32x4){k0, k0, k0, k0};
            accv[mt][nt] = (f32x4){v0, v0, v0, v0};
        }
    }
    #pragma unroll
    for (int kt = 0; kt < 4; ++kt) {
        int klane = kt * 32 + quad * 8;
        bf16x8 a0 = *(const bf16x8*)(xs + (l16)      * XP + klane);
        bf16x8 a1 = *(const bf16x8*)(xs + (16 + l16) * XP + klane);
        #pragma unroll
        for (int nt = 0; nt < 2; ++nt) {
            int c = wave * 32 + nt * 16 + l16;
            bf16x8 fq = *(const bf16x8*)(Wtq + (size_t)c * D + klane);
            bf16x8 fk = *(const bf16x8*)(Wtk + (size_t)c * D + klane);
            bf16x8 fv = *(const bf16x8*)(Wtv + (size_t)c * D + klane);
            accq[0][nt] = __builtin_amdgcn_mfma_f32_16x16x32_bf16(a0, fq, accq[0][nt], 0, 0, 0);
            accq[1][nt] = __builtin_amdgcn_mfma_f32_16x16x32_bf16(a1, fq, accq[1][nt], 0, 0, 0);
            acck[0][nt] = __builtin_amdgcn_mfma_f32_16x16x32_bf16(a0, fk, acck[0][nt], 0, 0, 0);
            acck[1][nt] = __builtin_amdgcn_mfma_f32_16x16x32_bf16(a1, fk, acck[1][nt], 0, 0, 0);
            accv[0][nt] = __builtin_amdgcn_mfma_f32_16x16x32_bf16(a0, fv, accv[0][nt], 0, 0, 0);
            accv[1][nt] = __builtin_amdgcn_mfma_f32_16x16x32_bf16(a1, fv, accv[1][nt], 0, 0, 0);
        }
    }
    #pragma unroll
    for (int mt = 0; mt < 2; ++mt)
        #pragma unroll
        for (int nt = 0; nt < 2; ++nt)
            #pragma unroll
            for (int r = 0; r < 4; ++r) {
                int row = mt * 16 + quad * 4 + r;
                int n = m0 + row;
                int c = wave * 32 + nt * 16 + l16;
                if (n < N) q[(size_t)n * D + c] = accq[mt][nt][r];
                int base = row * KVB + 16 * (c >> 3) + (c & 7);
                kvs[base]     = f2fp8(acck[mt][nt][r]);
                kvs[base + 8] = f2fp8(accv[mt][nt][r]);
            }
    __syncthreads();
    {   // coop write-out: 8 threads per row, 32 B each
        int row = t >> 3, c0 = (t & 7) * 32;
        int n = m0 + row;
        if (n < N) {
            *(uint4*)(kv + (size_t)n * 256 + c0) =
                *(const uint4*)(kvs + row * KVB + c0);
            *(uint4*)(kv + (size_t)n * 256 + c0 + 16) =
                *(const uint4*)(kvs + row * KVB + c0 + 16);
        }
    }
}

// ---------- CSR build ----------
__global__ void k_hist(const int* __restrict__ dst, int* __restrict__ deg, int E) {
    int i = blockIdx.x * blockDim.x + threadIdx.x;
    if (i < E) atomicAdd(&deg[dst[i]], 1);
}

__global__ void k_scan1(const int* __restrict__ deg, int* __restrict__ partial, int N) {
    __shared__ int red[256];
    int b = blockIdx.x, t = threadIdx.x;
    int base = b * SCB + t * 4;
    int s = 0;
    #pragma unroll
    for (int i = 0; i < 4; ++i) { int idx = base + i; if (idx < N) s += deg[idx]; }
    red[t] = s;
    __syncthreads();
    for (int off = 128; off > 0; off >>= 1) {
        if (t < off) red[t] += red[t + off];
        __syncthreads();
    }
    if (t == 0) partial[b] = red[0];
}

__global__ void k_scan2(int* __restrict__ partial, int nb) {
    __shared__ int s[256];
    int t = threadIdx.x;
    int v0 = (t < nb) ? partial[t] : 0;
    s[t] = v0;
    __syncthreads();
    for (int off = 1; off < 256; off <<= 1) {
        int v = (t >= off) ? s[t - off] : 0;
        __syncthreads();
        s[t] += v;
        __syncthreads();
    }
    if (t < nb) partial[t] = s[t] - v0;
    if (t == nb - 1) partial[nb] = s[t];
}

__global__ void k_scan3(const int* __restrict__ deg, const int* __restrict__ partial,
                        int* __restrict__ row_ptr, int* __restrict__ cursor,
                        int N, int nb) {
    __shared__ int red[256];
    int b = blockIdx.x, t = threadIdx.x;
    int base = b * SCB + t * 4;
    int d0[4]; int s = 0;
    #pragma unroll
    for (int i = 0; i < 4; ++i) {
        int idx = base + i;
        d0[i] = (idx < N) ? deg[idx] : 0;
        s += d0[i];
    }
    red[t] = s;
    __syncthreads();
    for (int off = 1; off < 256; off <<= 1) {
        int v = (t >= off) ? red[t - off] : 0;
        __syncthreads();
        red[t] += v;
        __syncthreads();
    }
    int off0 = partial[b] + red[t] - s;
    #pragma unroll
    for (int i = 0; i < 4; ++i) {
        int idx = base + i;
        if (idx < N) { row_ptr[idx] = off0; cursor[idx] = off0; off0 += d0[i]; }
    }
    if (b == 0 && t == 0) row_ptr[N] = partial[nb];
}

__global__ void k_scatter(const int* __restrict__ src, const int* __restrict__ dst,
                          int* __restrict__ cursor, int* __restrict__ col, int E) {
    int i = blockIdx.x * blockDim.x + threadIdx.x;
    if (i < E) {
        int d = dst[i];
        int pos = atomicAdd(&cursor[d], 1);
        col[pos] = src[i];
    }
}

// ---------- fused attention: 4 edges/iteration, agg stored bf16 ----------
__global__ void k_attn(const float* __restrict__ q, const unsigned char* __restrict__ kv,
                       const int* __restrict__ row_ptr, const int* __restrict__ col,
                       short* __restrict__ aggb, int N) {
    int wave = threadIdx.x >> 6;
    int lane = threadIdx.x & 63;
    int g = lane >> 4, s = lane & 15;
    int n = blockIdx.x * WPB + wave;
    if (n >= N) return;
    int beg = row_ptr[n], end = row_ptr[n + 1];

    float4 qa = *(const float4*)(q + (size_t)n * D + 8 * s);
    float4 qb = *(const float4*)(q + (size_t)n * D + 8 * s + 4);

    float acc[8] = {0.f, 0.f, 0.f, 0.f, 0.f, 0.f, 0.f, 0.f};
    float l = 0.f;

    int np = (end - beg + 3) >> 2;
    uint4 pk_cur = {0, 0, 0, 0};
    int idx_next = 0;
    if (np > 0) {
        int c0 = col[min(beg + g, end - 1)];
        pk_cur = *(const uint4*)(kv + (size_t)c0 * 256 + 16 * s);
        if (np > 1) idx_next = col[min(beg + 4 + g, end - 1)];
    }
    for (int it = 0; it < np; ++it) {
        uint4 pk = pk_cur;
        bool valid = (beg + it * 4 + g) < end;
        if (it + 1 < np) {
            pk_cur = *(const uint4*)(kv + (size_t)idx_next * 256 + 16 * s);
            if (it + 2 < np)
                idx_next = col[min(beg + (it + 2) * 4 + g, end - 1)];
        }
        f32x2 k01 = __builtin_amdgcn_cvt_pk_f32_fp8((int)pk.x, false);
        f32x2 k23 = __builtin_amdgcn_cvt_pk_f32_fp8((int)pk.x, true);
        f32x2 k45 = __builtin_amdgcn_cvt_pk_f32_fp8((int)pk.y, false);
        f32x2 k67 = __builtin_amdgcn_cvt_pk_f32_fp8((int)pk.y, true);
        f32x2 v01 = __builtin_amdgcn_cvt_pk_f32_fp8((int)pk.z, false);
        f32x2 v23 = __builtin_amdgcn_cvt_pk_f32_fp8((int)pk.z, true);
        f32x2 v45 = __builtin_amdgcn_cvt_pk_f32_fp8((int)pk.w, false);
        f32x2 v67 = __builtin_amdgcn_cvt_pk_f32_fp8((int)pk.w, true);
        float d = qa.x * k01.x + qa.y * k01.y + qa.z * k23.x + qa.w * k23.y
                + qb.x * k45.x + qb.y * k45.y + qb.z * k67.x + qb.w * k67.y;
        d += __shfl_xor(d, 1);
        d += __shfl_xor(d, 2);
        float pe = __expf(d * 0.17677669529663687f);
        pe = valid ? pe : 0.f;
        l += pe;
        acc[0] = fmaf(pe, v01.x, acc[0]);
        acc[1] = fmaf(pe, v01.y, acc[1]);
        acc[2] = fmaf(pe, v23.x, acc[2]);
        acc[3] = fmaf(pe, v23.y, acc[3]);
        acc[4] = fmaf(pe, v45.x, acc[4]);
        acc[5] = fmaf(pe, v45.y, acc[5]);
        acc[6] = fmaf(pe, v67.x, acc[6]);
        acc[7] = fmaf(pe, v67.y, acc[7]);
    }
    #pragma unroll
    for (int m = 16; m <= 32; m <<= 1) {
        l += __shfl_xor(l, m);
        #pragma unroll
        for (int i = 0; i < 8; ++i) acc[i] += __shfl_xor(acc[i], m);
    }
    if (g == 0) {
        float inv = (l > 0.f) ? 1.f / l : 0.f;
        bf16x8 o;
        #pragma unroll
        for (int i = 0; i < 8; ++i) o[i] = f2b(acc[i] * inv);
        *(bf16x8*)(aggb + (size_t)n * D + 8 * s) = o;
    }
}

// ---------- K56 (fused MFMA, wave-independent, ZERO barriers) ----------
// 64 nodes/block, 4 waves; each wave privately owns 16 rows end-to-end.
// A-frags: Wo phase direct from global bf16 agg; ln/hid tiles in wave-private LDS
// (ordering is in-wave lgkmcnt, no s_barrier). Hidden processed in 4x128-col quarters.
__global__ __launch_bounds__(256) void k56_wo_ln_mlp(
        const short* __restrict__ aggb, const short* __restrict__ Wto,
        const float* __restrict__ bo, const float* __restrict__ x,
        const float* __restrict__ g, const float* __restrict__ b,
        const short* __restrict__ Wt1, const float* __restrict__ b1,
        const short* __restrict__ Wt2, const float* __restrict__ b2,
        float* __restrict__ out, int N) {
    __shared__ short lns[4 * 16 * XP];    // per-wave ln tile  [16][136] bf16
    __shared__ short hids[4 * 16 * XP];   // per-wave hid quarter [16][136] bf16
    int t = threadIdx.x;
    int wave = t >> 6, lane = t & 63, quad = lane >> 4, l16 = lane & 15;
    int base = blockIdx.x * 64 + wave * 16;
    short* lnt  = lns  + wave * 16 * XP;
    short* hidt = hids + wave * 16 * XP;

    // ---- phase A: C = agg @ Wo + bo  (A direct from global bf16)
    f32x4 acc[8];
    #pragma unroll
    for (int nt = 0; nt < 8; ++nt) {
        float bb = bo[nt * 16 + l16];
        acc[nt] = (f32x4){bb, bb, bb, bb};
    }
    int arow = min(base + l16, N - 1);
    #pragma unroll
    for (int kt = 0; kt < 4; ++kt) {
        bf16x8 a = *(const bf16x8*)(aggb + (size_t)arow * D + kt * 32 + quad * 8);
        #pragma unroll
        for (int nt = 0; nt < 8; ++nt) {
            bf16x8 bf = *(const bf16x8*)(Wto + (size_t)(nt * 16 + l16) * D + kt * 32 + quad * 8);
            acc[nt] = __builtin_amdgcn_mfma_f32_16x16x32_bf16(a, bf, acc[nt], 0, 0, 0);
        }
    }
    // residual
    float lnv[8][4];
    #pragma unroll
    for (int r = 0; r < 4; ++r) {
        int nr = min(base + quad * 4 + r, N - 1);
        #pragma unroll
        for (int nt = 0; nt < 8; ++nt)
            lnv[nt][r] = acc[nt][r] + x[(size_t)nr * D + nt * 16 + l16];
    }
    // LN: wave-local stats (shfl over 16-lane group), apply, write bf16 tile
    #pragma unroll
    for (int r = 0; r < 4; ++r) {
        float s1 = 0.f, s2 = 0.f;
        #pragma unroll
        for (int nt = 0; nt < 8; ++nt) {
            float v = lnv[nt][r];
            s1 += v; s2 += v * v;
        }
        #pragma unroll
        for (int m = 1; m <= 8; m <<= 1) {
            s1 += __shfl_xor(s1, m);
            s2 += __shfl_xor(s2, m);
        }
        float mm = s1 * (1.0f / D), m2 = s2 * (1.0f / D);
        float rs = rsqrtf(m2 - mm * mm + 1e-5f);
        int row = quad * 4 + r;
        #pragma unroll
        for (int nt = 0; nt < 8; ++nt) {
            int c = nt * 16 + l16;
            float v = (lnv[nt][r] - mm) * rs * g[c] + b[c];
            lnt[row * XP + c] = f2b(v);
        }
    }

    // ---- phase B: MLP over 4 hidden quarters (128 cols each)
    f32x4 acc2[8];
    #pragma unroll
    for (int nt = 0; nt < 8; ++nt) {
        float bb = b2[nt * 16 + l16];
        acc2[nt] = (f32x4){bb, bb, bb, bb};
    }
    bf16x8 la[4];
    #pragma unroll
    for (int kt = 0; kt < 4; ++kt)
        la[kt] = *(const bf16x8*)(lnt + l16 * XP + kt * 32 + quad * 8);

    #pragma unroll
    for (int h = 0; h < 4; ++h) {
        // B1: hid quarter = gelu(ln @ W1[:, h*128 : h*128+128] + b1)
        f32x4 acc1[8];
        #pragma unroll
        for (int j = 0; j < 8; ++j) {
            float bb = b1[h * 128 + j * 16 + l16];
            acc1[j] = (f32x4){bb, bb, bb, bb};
        }
        #pragma unroll
        for (int kt = 0; kt < 4; ++kt) {
            #pragma unroll
            for (int j = 0; j < 8; ++j) {
                bf16x8 bf = *(const bf16x8*)(Wt1 + (size_t)(h * 128 + j * 16 + l16) * D
                                             + kt * 32 + quad * 8);
                acc1[j] = __builtin_amdgcn_mfma_f32_16x16x32_bf16(la[kt], bf, acc1[j], 0, 0, 0);
            }
        }
        #pragma unroll
        for (int j = 0; j < 8; ++j)
            #pragma unroll
            for (int r = 0; r < 4; ++r) {
                int row = quad * 4 + r;
                hidt[row * XP + j * 16 + l16] = f2b(gelu_tanh(acc1[j][r]));
            }
        // B2 partial: K range [h*128, h*128+128)
        #pragma unroll
        for (int kt = 0; kt < 4; ++kt) {
            bf16x8 ha = *(const bf16x8*)(hidt + l16 * XP + kt * 32 + quad * 8);
            #pragma unroll
            for (int nt = 0; nt < 8; ++nt) {
                bf16x8 bf = *(const bf16x8*)(Wt2 + (size_t)(nt * 16 + l16) * HID
                                             + h * 128 + kt * 32 + quad * 8);
                acc2[nt] = __builtin_amdgcn_mfma_f32_16x16x32_bf16(ha, bf, acc2[nt], 0, 0, 0);
            }
        }
    }

    // ---- store: out = ln (bf16 tile) + mlp
    #pragma unroll
    for (int r = 0; r < 4; ++r) {
        int row = quad * 4 + r;
        int n = base + row;
        if (n < N) {
            #pragma unroll
            for (int nt = 0; nt < 8; ++nt) {
                int c = nt * 16 + l16;
                out[(size_t)n * D + c] = b2f(lnt[row * XP + c]) + acc2[nt][r];
            }
        }
    }
}

// ---------- launch ----------
extern "C" void kernel_launch(void* const* d_in, const int* in_sizes, int n_in,
                              void* d_out, int out_size, void* d_ws, size_t ws_size,
                              hipStream_t stream) {
    const float* x   = (const float*)d_in[0];
    const int*   ei  = (const int*)d_in[1];
    const float* Wq  = (const float*)d_in[2];
    const float* bq  = (const float*)d_in[3];
    const float* Wk  = (const float*)d_in[4];
    const float* bk  = (const float*)d_in[5];
    const float* Wv  = (const float*)d_in[6];
    const float* bv  = (const float*)d_in[7];
    const float* Wo  = (const float*)d_in[8];
    const float* bo  = (const float*)d_in[9];
    const float* lng = (const float*)d_in[10];
    const float* lnb = (const float*)d_in[11];
    const float* W1  = (const float*)d_in[12];
    const float* b1  = (const float*)d_in[13];
    const float* W2  = (const float*)d_in[14];
    const float* b2  = (const float*)d_in[15];
    float* out = (float*)d_out;

    int N = in_sizes[0] / D;
    int E = in_sizes[1] / 2;
    const int* srcp = ei;
    const int* dstp = ei + E;

    // workspace layout
    short* Wt1 = (short*)d_ws;                 // 512*128
    short* Wt2 = Wt1 + 512 * 128;              // 128*512
    short* Wtq = Wt2 + 512 * 128;              // 128*128
    short* Wtk = Wtq + 128 * 128;
    short* Wtv = Wtk + 128 * 128;
    short* Wto = Wtv + 128 * 128;
    float* q   = (float*)(Wto + 128 * 128);    // N*D fp32
    unsigned char* kv = (unsigned char*)(q + (size_t)N * D);  // N*256 bytes fp8
    short* aggb = (short*)(kv + (size_t)N * 256);             // N*D bf16
    int*   deg     = (int*)(aggb + (size_t)N * D);
    int*   row_ptr = deg + N;                  // N+1
    int*   cursor  = row_ptr + N + 1;
    int*   col     = cursor + N;               // E
    int*   partial = col + E;                  // nbs+1

    int nblk32 = (N + MT - 1) / MT;
    int nblk64 = (N + 63) / 64;
    int eblk   = (E + 255) / 256;
    int nbs    = (N + SCB - 1) / SCB;

    k0_zero_deg<<<(N + 255) / 256, 256, 0, stream>>>(deg, N);
    k_prep<<<(512 * 128) / 256, 256, 0, stream>>>(W1, W2, Wq, Wk, Wv, Wo,
                                                  Wt1, Wt2, Wtq, Wtk, Wtv, Wto);
    k_hist<<<eblk, 256, 0, stream>>>(dstp, deg, E);
    k1_qkv_mfma<<<nblk32, 256, 0, stream>>>(x, Wtq, bq, Wtk, bk, Wtv, bv, q, kv, N);
    k_scan1<<<nbs, 256, 0, stream>>>(deg, partial, N);
    k_scan2<<<1, 256, 0, stream>>>(partial, nbs);
    k_scan3<<<nbs, 256, 0, stream>>>(deg, partial, row_ptr, cursor, N, nbs);
    k_scatter<<<eblk, 256, 0, stream>>>(srcp, dstp, cursor, col, E);
    k_attn<<<(N + WPB - 1) / WPB, WPB * 64, 0, stream>>>(q, kv, row_ptr, col, aggb, N);
    k56_wo_ln_mlp<<<nblk64, 256, 0, stream>>>(aggb, Wto, bo, x, lng, lnb,
                                              Wt1, b1, Wt2, b2, out, N);
}

// Round 10
// 261.635 us; speedup vs baseline: 1.3101x; 1.3101x over previous
//
#include <hip/hip_runtime.h>
#include <math.h>

#define D   128
#define HH  4
#define HD  32
#define HID 512
#define WPB 4     // nodes (waves) per block in fused attention
#define MT  32    // node tile for MFMA kernels
#define XP  136   // 128+8 padded LDS row (bf16 elems)
#define HHP 264   // 256+8 padded half-hidden row (bf16 elems)
#define KVB 264   // 256+8 padded kv LDS row (bytes)
#define SCB 1024  // elems per scan block

typedef __attribute__((ext_vector_type(8))) short bf16x8;  // 8 bf16 (4 VGPRs)
typedef __attribute__((ext_vector_type(4))) float f32x4;   // MFMA C/D frag
typedef __attribute__((ext_vector_type(2))) float f32x2;

// fp32 -> bf16 bits, round-to-nearest-even
__device__ __forceinline__ short f2b(float f) {
    unsigned u = __float_as_uint(f);
    unsigned r = (u + 0x7FFFu + ((u >> 16) & 1u)) >> 16;
    return (short)r;
}
__device__ __forceinline__ float b2f(short s) {
    return __uint_as_float(((unsigned)(unsigned short)s) << 16);
}
// fp32 -> fp8 e4m3 (OCP on gfx950), via hw packed cvt
__device__ __forceinline__ unsigned char f2fp8(float f) {
    return (unsigned char)(__builtin_amdgcn_cvt_pk_fp8_f32(f, f, 0, false) & 0xFF);
}

// gelu tanh-approx via hw exp: 0.5x(1+tanh u) = x*e^{2u}/(e^{2u}+1)
__device__ __forceinline__ float gelu_tanh(float x) {
    float u = 0.7978845608028654f * (x + 0.044715f * x * x * x);
    float e = __expf(2.0f * u);
    return x * e * __builtin_amdgcn_rcpf(e + 1.0f);
}

// ---------- K0: zero degree array ----------
__global__ void k0_zero_deg(int* __restrict__ deg, int N) {
    int i = blockIdx.x * blockDim.x + threadIdx.x;
    if (i < N) deg[i] = 0;
}

// ---------- prep: all weights -> bf16 transposed [n][k] ----------
__global__ void k_prep(const float* __restrict__ W1, const float* __restrict__ W2,
                       const float* __restrict__ Wq, const float* __restrict__ Wk,
                       const float* __restrict__ Wv, const float* __restrict__ Wo,
                       short* __restrict__ Wt1, short* __restrict__ Wt2,
                       short* __restrict__ Wtq, short* __restrict__ Wtk,
                       short* __restrict__ Wtv, short* __restrict__ Wto) {
    int i = blockIdx.x * 256 + threadIdx.x;     // 65536 threads
    {   int n = i >> 7, k = i & 127; Wt1[i] = f2b(W1[k * HID + n]); }
    {   int n = i >> 9, k = i & 511; Wt2[i] = f2b(W2[k * D + n]); }
    if (i < D * D) {
        int n = i >> 7, k = i & 127;
        Wtq[i] = f2b(Wq[k * D + n]);
        Wtk[i] = f2b(Wk[k * D + n]);
        Wtv[i] = f2b(Wv[k * D + n]);
        Wto[i] = f2b(Wo[k * D + n]);
    }
}

// ---------- K1 (MFMA): q fp32, kv fp8 in 8-dim blocks ----------
__global__ __launch_bounds__(256) void k1_qkv_mfma(
        const float* __restrict__ x,
        const short* __restrict__ Wtq, const float* __restrict__ bq,
        const short* __restrict__ Wtk, const float* __restrict__ bk,
        const short* __restrict__ Wtv, const float* __restrict__ bv,
        float* __restrict__ q, unsigned char* __restrict__ kv, int N) {
    __shared__ short xs[MT * XP];
    __shared__ unsigned char kvs[MT * KVB];
    int m0 = blockIdx.x * MT;
    int t = threadIdx.x;
    int wave = t >> 6, lane = t & 63, quad = lane >> 4, l16 = lane & 15;

    {
        int row = t >> 3, c0 = (t & 7) * 16;
        int n = m0 + row;
        #pragma unroll
        for (int c = 0; c < 16; c += 4) {
            float4 xv = {0.f, 0.f, 0.f, 0.f};
            if (n < N) xv = *(const float4*)(x + (size_t)n * D + c0 + c);
            xs[row * XP + c0 + c + 0] = f2b(xv.x);
            xs[row * XP + c0 + c + 1] = f2b(xv.y);
            xs[row * XP + c0 + c + 2] = f2b(xv.z);
            xs[row * XP + c0 + c + 3] = f2b(xv.w);
        }
    }
    __syncthreads();

    f32x4 accq[2][2], acck[2][2], accv[2][2];
    #pragma unroll
    for (int nt = 0; nt < 2; ++nt) {
        int c = wave * 32 + nt * 16 + l16;
        float q0 = bq[c], k0 = bk[c], v0 = bv[c];
        #pragma unroll
        for (int mt = 0; mt < 2; ++mt) {
            accq[mt][nt] = (f32x4){q0, q0, q0, q0};
            acck[mt][nt] = (f32x4){k0, k0, k0, k0};
            accv[mt][nt] = (f32x4){v0, v0, v0, v0};
        }
    }
    #pragma unroll
    for (int kt = 0; kt < 4; ++kt) {
        int klane = kt * 32 + quad * 8;
        bf16x8 a0 = *(const bf16x8*)(xs + (l16)      * XP + klane);
        bf16x8 a1 = *(const bf16x8*)(xs + (16 + l16) * XP + klane);
        #pragma unroll
        for (int nt = 0; nt < 2; ++nt) {
            int c = wave * 32 + nt * 16 + l16;
            bf16x8 fq = *(const bf16x8*)(Wtq + (size_t)c * D + klane);
            bf16x8 fk = *(const bf16x8*)(Wtk + (size_t)c * D + klane);
            bf16x8 fv = *(const bf16x8*)(Wtv + (size_t)c * D + klane);
            accq[0][nt] = __builtin_amdgcn_mfma_f32_16x16x32_bf16(a0, fq, accq[0][nt], 0, 0, 0);
            accq[1][nt] = __builtin_amdgcn_mfma_f32_16x16x32_bf16(a1, fq, accq[1][nt], 0, 0, 0);
            acck[0][nt] = __builtin_amdgcn_mfma_f32_16x16x32_bf16(a0, fk, acck[0][nt], 0, 0, 0);
            acck[1][nt] = __builtin_amdgcn_mfma_f32_16x16x32_bf16(a1, fk, acck[1][nt], 0, 0, 0);
            accv[0][nt] = __builtin_amdgcn_mfma_f32_16x16x32_bf16(a0, fv, accv[0][nt], 0, 0, 0);
            accv[1][nt] = __builtin_amdgcn_mfma_f32_16x16x32_bf16(a1, fv, accv[1][nt], 0, 0, 0);
        }
    }
    #pragma unroll
    for (int mt = 0; mt < 2; ++mt)
        #pragma unroll
        for (int nt = 0; nt < 2; ++nt)
            #pragma unroll
            for (int r = 0; r < 4; ++r) {
                int row = mt * 16 + quad * 4 + r;
                int n = m0 + row;
                int c = wave * 32 + nt * 16 + l16;
                if (n < N) q[(size_t)n * D + c] = accq[mt][nt][r];
                int base = row * KVB + 16 * (c >> 3) + (c & 7);
                kvs[base]     = f2fp8(acck[mt][nt][r]);
                kvs[base + 8] = f2fp8(accv[mt][nt][r]);
            }
    __syncthreads();
    {   // coop write-out: 8 threads per row, 32 B each
        int row = t >> 3, c0 = (t & 7) * 32;
        int n = m0 + row;
        if (n < N) {
            *(uint4*)(kv + (size_t)n * 256 + c0) =
                *(const uint4*)(kvs + row * KVB + c0);
            *(uint4*)(kv + (size_t)n * 256 + c0 + 16) =
                *(const uint4*)(kvs + row * KVB + c0 + 16);
        }
    }
}

// ---------- CSR build ----------
__global__ void k_hist(const int* __restrict__ dst, int* __restrict__ deg, int E) {
    int i = blockIdx.x * blockDim.x + threadIdx.x;
    if (i < E) atomicAdd(&deg[dst[i]], 1);
}

__global__ void k_scan1(const int* __restrict__ deg, int* __restrict__ partial, int N) {
    __shared__ int red[256];
    int b = blockIdx.x, t = threadIdx.x;
    int base = b * SCB + t * 4;
    int s = 0;
    #pragma unroll
    for (int i = 0; i < 4; ++i) { int idx = base + i; if (idx < N) s += deg[idx]; }
    red[t] = s;
    __syncthreads();
    for (int off = 128; off > 0; off >>= 1) {
        if (t < off) red[t] += red[t + off];
        __syncthreads();
    }
    if (t == 0) partial[b] = red[0];
}

__global__ void k_scan2(int* __restrict__ partial, int nb) {
    __shared__ int s[256];
    int t = threadIdx.x;
    int v0 = (t < nb) ? partial[t] : 0;
    s[t] = v0;
    __syncthreads();
    for (int off = 1; off < 256; off <<= 1) {
        int v = (t >= off) ? s[t - off] : 0;
        __syncthreads();
        s[t] += v;
        __syncthreads();
    }
    if (t < nb) partial[t] = s[t] - v0;
    if (t == nb - 1) partial[nb] = s[t];
}

__global__ void k_scan3(const int* __restrict__ deg, const int* __restrict__ partial,
                        int* __restrict__ row_ptr, int* __restrict__ cursor,
                        int N, int nb) {
    __shared__ int red[256];
    int b = blockIdx.x, t = threadIdx.x;
    int base = b * SCB + t * 4;
    int d0[4]; int s = 0;
    #pragma unroll
    for (int i = 0; i < 4; ++i) {
        int idx = base + i;
        d0[i] = (idx < N) ? deg[idx] : 0;
        s += d0[i];
    }
    red[t] = s;
    __syncthreads();
    for (int off = 1; off < 256; off <<= 1) {
        int v = (t >= off) ? red[t - off] : 0;
        __syncthreads();
        red[t] += v;
        __syncthreads();
    }
    int off0 = partial[b] + red[t] - s;
    #pragma unroll
    for (int i = 0; i < 4; ++i) {
        int idx = base + i;
        if (idx < N) { row_ptr[idx] = off0; cursor[idx] = off0; off0 += d0[i]; }
    }
    if (b == 0 && t == 0) row_ptr[N] = partial[nb];
}

__global__ void k_scatter(const int* __restrict__ src, const int* __restrict__ dst,
                          int* __restrict__ cursor, int* __restrict__ col, int E) {
    int i = blockIdx.x * blockDim.x + threadIdx.x;
    if (i < E) {
        int d = dst[i];
        int pos = atomicAdd(&cursor[d], 1);
        col[pos] = src[i];
    }
}

// ---------- fused attention: 4 edges/iteration, agg stored bf16 ----------
__global__ void k_attn(const float* __restrict__ q, const unsigned char* __restrict__ kv,
                       const int* __restrict__ row_ptr, const int* __restrict__ col,
                       short* __restrict__ aggb, int N) {
    int wave = threadIdx.x >> 6;
    int lane = threadIdx.x & 63;
    int g = lane >> 4, s = lane & 15;
    int n = blockIdx.x * WPB + wave;
    if (n >= N) return;
    int beg = row_ptr[n], end = row_ptr[n + 1];

    float4 qa = *(const float4*)(q + (size_t)n * D + 8 * s);
    float4 qb = *(const float4*)(q + (size_t)n * D + 8 * s + 4);

    float acc[8] = {0.f, 0.f, 0.f, 0.f, 0.f, 0.f, 0.f, 0.f};
    float l = 0.f;

    int np = (end - beg + 3) >> 2;
    uint4 pk_cur = {0, 0, 0, 0};
    int idx_next = 0;
    if (np > 0) {
        int c0 = col[min(beg + g, end - 1)];
        pk_cur = *(const uint4*)(kv + (size_t)c0 * 256 + 16 * s);
        if (np > 1) idx_next = col[min(beg + 4 + g, end - 1)];
    }
    for (int it = 0; it < np; ++it) {
        uint4 pk = pk_cur;
        bool valid = (beg + it * 4 + g) < end;
        if (it + 1 < np) {
            pk_cur = *(const uint4*)(kv + (size_t)idx_next * 256 + 16 * s);
            if (it + 2 < np)
                idx_next = col[min(beg + (it + 2) * 4 + g, end - 1)];
        }
        f32x2 k01 = __builtin_amdgcn_cvt_pk_f32_fp8((int)pk.x, false);
        f32x2 k23 = __builtin_amdgcn_cvt_pk_f32_fp8((int)pk.x, true);
        f32x2 k45 = __builtin_amdgcn_cvt_pk_f32_fp8((int)pk.y, false);
        f32x2 k67 = __builtin_amdgcn_cvt_pk_f32_fp8((int)pk.y, true);
        f32x2 v01 = __builtin_amdgcn_cvt_pk_f32_fp8((int)pk.z, false);
        f32x2 v23 = __builtin_amdgcn_cvt_pk_f32_fp8((int)pk.z, true);
        f32x2 v45 = __builtin_amdgcn_cvt_pk_f32_fp8((int)pk.w, false);
        f32x2 v67 = __builtin_amdgcn_cvt_pk_f32_fp8((int)pk.w, true);
        float d = qa.x * k01.x + qa.y * k01.y + qa.z * k23.x + qa.w * k23.y
                + qb.x * k45.x + qb.y * k45.y + qb.z * k67.x + qb.w * k67.y;
        d += __shfl_xor(d, 1);
        d += __shfl_xor(d, 2);
        float pe = __expf(d * 0.17677669529663687f);
        pe = valid ? pe : 0.f;
        l += pe;
        acc[0] = fmaf(pe, v01.x, acc[0]);
        acc[1] = fmaf(pe, v01.y, acc[1]);
        acc[2] = fmaf(pe, v23.x, acc[2]);
        acc[3] = fmaf(pe, v23.y, acc[3]);
        acc[4] = fmaf(pe, v45.x, acc[4]);
        acc[5] = fmaf(pe, v45.y, acc[5]);
        acc[6] = fmaf(pe, v67.x, acc[6]);
        acc[7] = fmaf(pe, v67.y, acc[7]);
    }
    #pragma unroll
    for (int m = 16; m <= 32; m <<= 1) {
        l += __shfl_xor(l, m);
        #pragma unroll
        for (int i = 0; i < 8; ++i) acc[i] += __shfl_xor(acc[i], m);
    }
    if (g == 0) {
        float inv = (l > 0.f) ? 1.f / l : 0.f;
        bf16x8 o;
        #pragma unroll
        for (int i = 0; i < 8; ++i) o[i] = f2b(acc[i] * inv);
        *(bf16x8*)(aggb + (size_t)n * D + 8 * s) = o;
    }
}

// ---------- K56 (fused MFMA, R8 structure + direct bf16 agg A-loads) ----------
// 32 nodes/block, 4 waves, col-split (wave owns out cols [wave*32,+32)); ln in
// registers + shared bf16 tile; hidden in two 256-col halves. 5 barriers.
__global__ __launch_bounds__(256) void k56_wo_ln_mlp(
        const short* __restrict__ aggb, const short* __restrict__ Wto,
        const float* __restrict__ bo, const float* __restrict__ x,
        const float* __restrict__ g, const float* __restrict__ b,
        const short* __restrict__ Wt1, const float* __restrict__ b1,
        const short* __restrict__ Wt2, const float* __restrict__ b2,
        float* __restrict__ out, int N) {
    __shared__ short xs[MT * XP];            // ln tile (bf16)
    __shared__ short hid[MT * HHP];          // half-hidden (bf16)
    __shared__ float ps[MT * 4], ps2[MT * 4];
    int m0 = blockIdx.x * MT;
    int t = threadIdx.x;
    int wave = t >> 6, lane = t & 63, quad = lane >> 4, l16 = lane & 15;

    // phase A: Wo GEMM; A-frags directly from global bf16 agg (N multiple of 32)
    f32x4 acc[2][2];
    #pragma unroll
    for (int nt = 0; nt < 2; ++nt) {
        float bb = bo[wave * 32 + nt * 16 + l16];
        acc[0][nt] = (f32x4){bb, bb, bb, bb};
        acc[1][nt] = (f32x4){bb, bb, bb, bb};
    }
    {
        const short* ar0 = aggb + (size_t)(m0 + l16) * D;
        const short* ar1 = aggb + (size_t)(m0 + 16 + l16) * D;
        #pragma unroll
        for (int kt = 0; kt < 4; ++kt) {
            int klane = kt * 32 + quad * 8;
            bf16x8 a0 = *(const bf16x8*)(ar0 + klane);
            bf16x8 a1 = *(const bf16x8*)(ar1 + klane);
            #pragma unroll
            for (int nt = 0; nt < 2; ++nt) {
                bf16x8 bf = *(const bf16x8*)(Wto + (size_t)(wave * 32 + nt * 16 + l16) * D + klane);
                acc[0][nt] = __builtin_amdgcn_mfma_f32_16x16x32_bf16(a0, bf, acc[0][nt], 0, 0, 0);
                acc[1][nt] = __builtin_amdgcn_mfma_f32_16x16x32_bf16(a1, bf, acc[1][nt], 0, 0, 0);
            }
        }
    }
    float lnval[2][2][4];
    #pragma unroll
    for (int mt = 0; mt < 2; ++mt)
        #pragma unroll
        for (int nt = 0; nt < 2; ++nt)
            #pragma unroll
            for (int r = 0; r < 4; ++r) {
                int n = m0 + mt * 16 + quad * 4 + r;
                int c = wave * 32 + nt * 16 + l16;
                lnval[mt][nt][r] = acc[mt][nt][r] + x[(size_t)n * D + c];
            }

    // LN stats: shfl over l16 group, LDS across waves
    #pragma unroll
    for (int mt = 0; mt < 2; ++mt)
        #pragma unroll
        for (int r = 0; r < 4; ++r) {
            float a0 = lnval[mt][0][r], a1 = lnval[mt][1][r];
            float s1 = a0 + a1;
            float s2 = a0 * a0 + a1 * a1;
            #pragma unroll
            for (int m = 1; m <= 8; m <<= 1) {
                s1 += __shfl_xor(s1, m);
                s2 += __shfl_xor(s2, m);
            }
            if (l16 == 0) {
                int row = mt * 16 + quad * 4 + r;
                ps[row * 4 + wave] = s1;
                ps2[row * 4 + wave] = s2;
            }
        }
    __syncthreads();

    #pragma unroll
    for (int mt = 0; mt < 2; ++mt)
        #pragma unroll
        for (int r = 0; r < 4; ++r) {
            int row = mt * 16 + quad * 4 + r;
            float4 p1 = *(const float4*)(ps + row * 4);
            float4 p2 = *(const float4*)(ps2 + row * 4);
            float mm = (p1.x + p1.y + p1.z + p1.w) * (1.0f / D);
            float m2 = (p2.x + p2.y + p2.z + p2.w) * (1.0f / D);
            float rs = rsqrtf(m2 - mm * mm + 1e-5f);
            #pragma unroll
            for (int nt = 0; nt < 2; ++nt) {
                int c = wave * 32 + nt * 16 + l16;
                float v = (lnval[mt][nt][r] - mm) * rs * g[c] + b[c];
                lnval[mt][nt][r] = v;
                xs[row * XP + c] = f2b(v);
            }
        }
    __syncthreads();

    // MLP in two 256-col hidden halves
    f32x4 acc2[2][2];
    #pragma unroll
    for (int nt = 0; nt < 2; ++nt) {
        float bb = b2[wave * 32 + nt * 16 + l16];
        acc2[0][nt] = (f32x4){bb, bb, bb, bb};
        acc2[1][nt] = (f32x4){bb, bb, bb, bb};
    }
    #pragma unroll
    for (int h = 0; h < 2; ++h) {
        f32x4 acc1[2][4];
        #pragma unroll
        for (int nt = 0; nt < 4; ++nt) {
            float bb = b1[h * 256 + wave * 64 + nt * 16 + l16];
            acc1[0][nt] = (f32x4){bb, bb, bb, bb};
            acc1[1][nt] = (f32x4){bb, bb, bb, bb};
        }
        #pragma unroll
        for (int kt = 0; kt < 4; ++kt) {
            int klane = kt * 32 + quad * 8;
            bf16x8 a0 = *(const bf16x8*)(xs + (l16)      * XP + klane);
            bf16x8 a1 = *(const bf16x8*)(xs + (16 + l16) * XP + klane);
            #pragma unroll
            for (int nt = 0; nt < 4; ++nt) {
                int hc = h * 256 + wave * 64 + nt * 16 + l16;
                bf16x8 bf = *(const bf16x8*)(Wt1 + (size_t)hc * D + klane);
                acc1[0][nt] = __builtin_amdgcn_mfma_f32_16x16x32_bf16(a0, bf, acc1[0][nt], 0, 0, 0);
                acc1[1][nt] = __builtin_amdgcn_mfma_f32_16x16x32_bf16(a1, bf, acc1[1][nt], 0, 0, 0);
            }
        }
        __syncthreads();   // prev half's hid fully consumed
        #pragma unroll
        for (int mt = 0; mt < 2; ++mt)
            #pragma unroll
            for (int nt = 0; nt < 4; ++nt)
                #pragma unroll
                for (int r = 0; r < 4; ++r) {
                    int row = mt * 16 + quad * 4 + r;
                    int lc = wave * 64 + nt * 16 + l16;
                    hid[row * HHP + lc] = f2b(gelu_tanh(acc1[mt][nt][r]));
                }
        __syncthreads();   // half-hidden ready
        #pragma unroll
        for (int kt = 0; kt < 8; ++kt) {
            int klane = kt * 32 + quad * 8;
            bf16x8 a0 = *(const bf16x8*)(hid + (l16)      * HHP + klane);
            bf16x8 a1 = *(const bf16x8*)(hid + (16 + l16) * HHP + klane);
            #pragma unroll
            for (int nt = 0; nt < 2; ++nt) {
                bf16x8 bf = *(const bf16x8*)(Wt2 + (size_t)(wave * 32 + nt * 16 + l16) * HID
                                             + h * 256 + klane);
                acc2[0][nt] = __builtin_amdgcn_mfma_f32_16x16x32_bf16(a0, bf, acc2[0][nt], 0, 0, 0);
                acc2[1][nt] = __builtin_amdgcn_mfma_f32_16x16x32_bf16(a1, bf, acc2[1][nt], 0, 0, 0);
            }
        }
    }

    #pragma unroll
    for (int mt = 0; mt < 2; ++mt)
        #pragma unroll
        for (int nt = 0; nt < 2; ++nt)
            #pragma unroll
            for (int r = 0; r < 4; ++r) {
                int n = m0 + mt * 16 + quad * 4 + r;
                int c = wave * 32 + nt * 16 + l16;
                if (n < N)
                    out[(size_t)n * D + c] = lnval[mt][nt][r] + acc2[mt][nt][r];
            }
}

// ---------- launch ----------
extern "C" void kernel_launch(void* const* d_in, const int* in_sizes, int n_in,
                              void* d_out, int out_size, void* d_ws, size_t ws_size,
                              hipStream_t stream) {
    const float* x   = (const float*)d_in[0];
    const int*   ei  = (const int*)d_in[1];
    const float* Wq  = (const float*)d_in[2];
    const float* bq  = (const float*)d_in[3];
    const float* Wk  = (const float*)d_in[4];
    const float* bk  = (const float*)d_in[5];
    const float* Wv  = (const float*)d_in[6];
    const float* bv  = (const float*)d_in[7];
    const float* Wo  = (const float*)d_in[8];
    const float* bo  = (const float*)d_in[9];
    const float* lng = (const float*)d_in[10];
    const float* lnb = (const float*)d_in[11];
    const float* W1  = (const float*)d_in[12];
    const float* b1  = (const float*)d_in[13];
    const float* W2  = (const float*)d_in[14];
    const float* b2  = (const float*)d_in[15];
    float* out = (float*)d_out;

    int N = in_sizes[0] / D;
    int E = in_sizes[1] / 2;
    const int* srcp = ei;
    const int* dstp = ei + E;

    // workspace layout
    short* Wt1 = (short*)d_ws;                 // 512*128
    short* Wt2 = Wt1 + 512 * 128;              // 128*512
    short* Wtq = Wt2 + 512 * 128;              // 128*128
    short* Wtk = Wtq + 128 * 128;
    short* Wtv = Wtk + 128 * 128;
    short* Wto = Wtv + 128 * 128;
    float* q   = (float*)(Wto + 128 * 128);    // N*D fp32
    unsigned char* kv = (unsigned char*)(q + (size_t)N * D);  // N*256 bytes fp8
    short* aggb = (short*)(kv + (size_t)N * 256);             // N*D bf16
    int*   deg     = (int*)(aggb + (size_t)N * D);
    int*   row_ptr = deg + N;                  // N+1
    int*   cursor  = row_ptr + N + 1;
    int*   col     = cursor + N;               // E
    int*   partial = col + E;                  // nbs+1

    int nblk32 = (N + MT - 1) / MT;
    int eblk   = (E + 255) / 256;
    int nbs    = (N + SCB - 1) / SCB;

    k0_zero_deg<<<(N + 255) / 256, 256, 0, stream>>>(deg, N);
    k_prep<<<(512 * 128) / 256, 256, 0, stream>>>(W1, W2, Wq, Wk, Wv, Wo,
                                                  Wt1, Wt2, Wtq, Wtk, Wtv, Wto);
    k_hist<<<eblk, 256, 0, stream>>>(dstp, deg, E);
    k1_qkv_mfma<<<nblk32, 256, 0, stream>>>(x, Wtq, bq, Wtk, bk, Wtv, bv, q, kv, N);
    k_scan1<<<nbs, 256, 0, stream>>>(deg, partial, N);
    k_scan2<<<1, 256, 0, stream>>>(partial, nbs);
    k_scan3<<<nbs, 256, 0, stream>>>(deg, partial, row_ptr, cursor, N, nbs);
    k_scatter<<<eblk, 256, 0, stream>>>(srcp, dstp, cursor, col, E);
    k_attn<<<(N + WPB - 1) / WPB, WPB * 64, 0, stream>>>(q, kv, row_ptr, col, aggb, N);
    k56_wo_ln_mlp<<<nblk32, 256, 0, stream>>>(aggb, Wto, bo, x, lng, lnb,
                                              Wt1, b1, Wt2, b2, out, N);
}